// Round 18
// baseline (374.710 us; speedup 1.0000x reference)
//
#include <hip/hip_runtime.h>

// ---------------------------------------------------------------------------
// MoNet GNN: N=50000, E=800000, H=128, K=3, L=4, pdim=2, G=50, npg=1000
// Round 18: agg main loop widened to 8 edges/iter (4x uint4 rec-pair loads,
//           8 gathers in flight) to halve the serial latency rounds per node;
//           masked-4 loop handles the tail. Rest identical to R17 (8-wave
//           512-thread GEMM, graph-level CSR, 8B bf16 records, fused BN).
// ---------------------------------------------------------------------------

typedef unsigned char  u8;
typedef unsigned short u16;
typedef unsigned int   u32;
typedef __attribute__((ext_vector_type(8))) short bf16x8;
typedef __attribute__((ext_vector_type(4))) float f32x4;

__device__ __forceinline__ u16 f2b(float f) {
    union { float f; u32 u; } v; v.f = f;
    u32 u = v.u;
    u32 r = (u + 0x7fffu + ((u >> 16) & 1u)) >> 16;   // RNE
    return (u16)r;
}
__device__ __forceinline__ float blo(u32 h) {
    union { u32 u; float f; } v; v.u = h << 16; return v.f;
}
__device__ __forceinline__ float bhi(u32 h) {
    union { u32 u; float f; } v; v.u = h & 0xffff0000u; return v.f;
}

// ---- merged weight prep: embW^T (16384 elems) then fcW B^T (L*128*384)
__global__ void prep_weights(const float* __restrict__ embW, u16* __restrict__ embT,
                             const float* __restrict__ fcW, u16* __restrict__ fcT,
                             int totalFc) {
    int idx = blockIdx.x * 256 + threadIdx.x;
    if (idx < 16384) {
        int n = idx >> 7, k = idx & 127;
        embT[idx] = f2b(embW[k * 128 + n]);
        return;
    }
    idx -= 16384;
    if (idx >= totalFc) return;
    int kk = idx % 384;
    int rest = idx / 384;
    int n = rest & 127;
    int l = rest >> 7;
    int kc = kk >> 7, r = kk & 127;
    fcT[idx] = f2b(fcW[((size_t)(l * 128 + r)) * 384 + kc * 128 + n]);
}

// ---- per-graph edge histogram (LDS-binned)
__global__ __launch_bounds__(256) void ghist_kernel(const int* __restrict__ dst,
                                                    int* __restrict__ gtot,
                                                    int E, int npg) {
    __shared__ int h[64];
    const int tid = threadIdx.x;
    if (tid < 64) h[tid] = 0;
    __syncthreads();
    int e0 = blockIdx.x * 4096;
    int n = min(4096, E - e0);
    for (int i = tid; i < n; i += 256) atomicAdd(&h[dst[e0 + i] / npg], 1);
    __syncthreads();
    if (tid < 64) { int v = h[tid]; if (v) atomicAdd(&gtot[tid], v); }
}

// ---- exclusive scan of gtot[G] -> gbase0[G+1]
__global__ void gscan_kernel(const int* __restrict__ gtot, int* __restrict__ gbase0, int G) {
    if (threadIdx.x == 0 && blockIdx.x == 0) {
        int acc = 0;
        for (int g = 0; g < G; g++) { gbase0[g] = acc; acc += gtot[g]; }
        gbase0[G] = acc;
    }
}

// ---- Pass A: bin 4096 edges per block by graph (LDS), chunk-copy to tmp
__global__ __launch_bounds__(256) void bucketA(const int* __restrict__ src,
                                               const int* __restrict__ dst,
                                               const int* __restrict__ gbase0,
                                               int* __restrict__ gcur,
                                               u32* __restrict__ tmp,
                                               int E, int npg, int G) {
    __shared__ u32 ebuf[4096];
    __shared__ u8  gmap[4096];
    __shared__ int ghist[64], gexc[64], gbase[64], lcur[64];
    const int tid = threadIdx.x;
    const int e0 = blockIdx.x * 4096;
    const int n = min(4096, E - e0);
    if (tid < 64) { ghist[tid] = 0; lcur[tid] = 0; }
    __syncthreads();
    for (int i = tid; i < n; i += 256) {
        int g = dst[e0 + i] / npg;
        atomicAdd(&ghist[g], 1);
    }
    __syncthreads();
    if (tid == 0) {
        int acc = 0;
        for (int g = 0; g < G; g++) { gexc[g] = acc; acc += ghist[g]; }
    }
    __syncthreads();
    if (tid < G) {
        int c = ghist[tid];
        gbase[tid] = (c > 0) ? gbase0[tid] + atomicAdd(&gcur[tid], c) : 0;
    }
    __syncthreads();
    for (int i = tid; i < n; i += 256) {
        int d = dst[e0 + i];
        int g = d / npg;
        int pos = gexc[g] + atomicAdd(&lcur[g], 1);
        ebuf[pos] = ((u32)src[e0 + i] << 16) | (u32)(d - g * npg);
        gmap[pos] = (u8)g;
    }
    __syncthreads();
    for (int i = tid; i < n; i += 256) {
        int g = gmap[i];
        tmp[gbase[g] + (i - gexc[g])] = ebuf[i];
    }
}

// ---- Pass B: one block per graph. Builds node-level rs (LDS hist + scan),
//      then counting-scatters psrc and fills pdst.
__global__ __launch_bounds__(1024) void bucketB(const u32* __restrict__ tmp,
                                                const int* __restrict__ gbase0,
                                                int* __restrict__ rs,
                                                int* __restrict__ psrc,
                                                int* __restrict__ pdst,
                                                int npg, int G, int N) {
    __shared__ int rsl[1025];
    __shared__ int lcur[1024];
    __shared__ int buf[1024];
    const int g = blockIdx.x, tid = threadIdx.x;
    const int base = g * npg;
    const int r0 = gbase0[g], r1 = gbase0[g + 1];
    if (tid < 1024) lcur[tid] = 0;
    __syncthreads();
    for (int p = r0 + tid; p < r1; p += 1024)
        atomicAdd(&lcur[tmp[p] & 0xffffu], 1);
    __syncthreads();
    int v = (tid < npg) ? lcur[tid] : 0;
    buf[tid] = v;
    __syncthreads();
    for (int off = 1; off < 1024; off <<= 1) {
        int x = (tid >= off) ? buf[tid - off] : 0;
        __syncthreads();
        buf[tid] += x;
        __syncthreads();
    }
    if (tid < npg) rsl[tid] = r0 + buf[tid] - v;
    if (tid == 0) rsl[npg] = r1;
    if (tid < 1024) lcur[tid] = 0;
    __syncthreads();
    for (int i = tid; i < npg; i += 1024) rs[base + i] = rsl[i];
    if (g == G - 1 && tid == 0) rs[N] = r1;
    for (int p = r0 + tid; p < r1; p += 1024) {
        u32 w = tmp[p];
        int dl = w & 0xffffu;
        int pos = rsl[dl] + atomicAdd(&lcur[dl], 1);
        psrc[pos] = (int)(w >> 16);
    }
    for (int i = tid; i < npg; i += 1024) {
        int a = rsl[i], b = rsl[i + 1];
        for (int p = a; p < b; p++) pdst[p] = base + i;
    }
}

// ---- build 8B edge records {u16 src | bf16 g0 <<16, bf16 g1 | bf16 g2 <<16}
__global__ void gw_kernel(const int* __restrict__ psrc, const int* __restrict__ pdst,
                          const int* __restrict__ rs,
                          const float* __restrict__ ppW, const float* __restrict__ ppb,
                          const float* __restrict__ mu, const float* __restrict__ isig,
                          uint2* __restrict__ rec, int E, int Epad, int L) {
    int p = blockIdx.x * 256 + threadIdx.x;
    if (p >= Epad) return;
    if (p >= E) {
        for (int l = 0; l < L; l++) rec[(size_t)l * Epad + p] = make_uint2(0u, 0u);
        return;
    }
    int s = psrc[p];
    int d = pdst[p];
    float ps0 = rsqrtf((float)(rs[s + 1] - rs[s]) + 1.0f);
    float ps1 = rsqrtf((float)(rs[d + 1] - rs[d]) + 1.0f);
    for (int l = 0; l < L; l++) {
        float p0 = tanhf(ps0 * ppW[l * 4 + 0] + ps1 * ppW[l * 4 + 2] + ppb[l * 2 + 0]);
        float p1 = tanhf(ps0 * ppW[l * 4 + 1] + ps1 * ppW[l * 4 + 3] + ppb[l * 2 + 1]);
        float g[3];
#pragma unroll
        for (int k = 0; k < 3; k++) {
            float d0 = (p0 - mu[(l * 3 + k) * 2 + 0]) * isig[(l * 3 + k) * 2 + 0];
            float d1 = (p1 - mu[(l * 3 + k) * 2 + 1]) * isig[(l * 3 + k) * 2 + 1];
            g[k] = expf(-0.5f * (d0 * d0 + d1 * d1));
        }
        uint2 r;
        r.x = (u32)s | ((u32)f2b(g[0]) << 16);
        r.y = (u32)f2b(g[1]) | ((u32)f2b(g[2]) << 16);
        rec[(size_t)l * Epad + p] = r;
    }
}

// ---- per-node aggregation: QUARTER-WAVE per node (16 lanes, 8 ch/lane).
//      Main: 8 edges/iter (4x uint4 rec-pair loads, 8 uint4 gathers in
//      flight). Tail: masked 4-edge blocks. No cross-lane reduce.
__global__ __launch_bounds__(256) void agg_kernel(const u16* __restrict__ hb,
                                                  const uint2* __restrict__ rec,  // layer base
                                                  const int* __restrict__ rs,
                                                  u16* __restrict__ t,
                                                  float* __restrict__ sk, int N) {
    int nid = blockIdx.x * 16 + (threadIdx.x >> 4);
    if (nid >= N) return;
    int lane = threadIdx.x & 15;         // channels lane*8 .. lane*8+7
    int p0 = rs[nid], p1 = rs[nid + 1];
    float a0[8] = {}, a1[8] = {}, a2[8] = {};
    float gs0 = 0.f, gs1 = 0.f, gs2 = 0.f;
    int p = p0;
    // 8-edge blocks: rec pairs as uint4 (rec is 8B, pairs are 16B-aligned
    // when p is even; p0 starts arbitrary so use two uint2 loads per pair
    // unless aligned — use uint4 only on even p)
    if (p & 1) {    // peel one edge to align to pair boundary
        uint2 rv = rec[p];
        int s = rv.x & 0xffff;
        uint4 hvv = *(const uint4*)(hb + (size_t)s * 128 + lane * 8);
        bool ok = p < p1;
        float g0 = ok ? bhi(rv.x) : 0.f;
        float g1 = ok ? blo(rv.y) : 0.f;
        float g2 = ok ? bhi(rv.y) : 0.f;
        float f[8];
        f[0] = blo(hvv.x); f[1] = bhi(hvv.x);
        f[2] = blo(hvv.y); f[3] = bhi(hvv.y);
        f[4] = blo(hvv.z); f[5] = bhi(hvv.z);
        f[6] = blo(hvv.w); f[7] = bhi(hvv.w);
#pragma unroll
        for (int c = 0; c < 8; c++) {
            a0[c] += g0 * f[c];
            a1[c] += g1 * f[c];
            a2[c] += g2 * f[c];
        }
        gs0 += g0; gs1 += g1; gs2 += g2;
        p++;
    }
    for (; p + 8 <= p1; p += 8) {
        uint4 rr[4];
        uint4 hv[8];
#pragma unroll
        for (int j = 0; j < 4; j++)
            rr[j] = *(const uint4*)(rec + p + 2 * j);   // 2 records each
#pragma unroll
        for (int j = 0; j < 4; j++) {
            int s0 = rr[j].x & 0xffff;
            int s1 = rr[j].z & 0xffff;
            hv[2 * j]     = *(const uint4*)(hb + (size_t)s0 * 128 + lane * 8);
            hv[2 * j + 1] = *(const uint4*)(hb + (size_t)s1 * 128 + lane * 8);
        }
#pragma unroll
        for (int j = 0; j < 8; j++) {
            u32 rx = (j & 1) ? rr[j >> 1].z : rr[j >> 1].x;
            u32 ry = (j & 1) ? rr[j >> 1].w : rr[j >> 1].y;
            float g0 = bhi(rx), g1 = blo(ry), g2 = bhi(ry);
            float f[8];
            f[0] = blo(hv[j].x); f[1] = bhi(hv[j].x);
            f[2] = blo(hv[j].y); f[3] = bhi(hv[j].y);
            f[4] = blo(hv[j].z); f[5] = bhi(hv[j].z);
            f[6] = blo(hv[j].w); f[7] = bhi(hv[j].w);
#pragma unroll
            for (int c = 0; c < 8; c++) {
                a0[c] += g0 * f[c];
                a1[c] += g1 * f[c];
                a2[c] += g2 * f[c];
            }
            gs0 += g0; gs1 += g1; gs2 += g2;
        }
    }
    // masked 4-edge blocks for the tail (rec zero-padded to Epad)
    for (; p < p1; p += 4) {
        uint2 rv[4];
        uint4 hv[4];
#pragma unroll
        for (int j = 0; j < 4; j++) rv[j] = rec[p + j];
#pragma unroll
        for (int j = 0; j < 4; j++) {
            int s = rv[j].x & 0xffff;
            hv[j] = *(const uint4*)(hb + (size_t)s * 128 + lane * 8);
        }
#pragma unroll
        for (int j = 0; j < 4; j++) {
            bool ok = (p + j) < p1;
            float g0 = ok ? bhi(rv[j].x) : 0.f;
            float g1 = ok ? blo(rv[j].y) : 0.f;
            float g2 = ok ? bhi(rv[j].y) : 0.f;
            float f[8];
            f[0] = blo(hv[j].x); f[1] = bhi(hv[j].x);
            f[2] = blo(hv[j].y); f[3] = bhi(hv[j].y);
            f[4] = blo(hv[j].z); f[5] = bhi(hv[j].z);
            f[6] = blo(hv[j].w); f[7] = bhi(hv[j].w);
#pragma unroll
            for (int c = 0; c < 8; c++) {
                a0[c] += g0 * f[c];
                a1[c] += g1 * f[c];
                a2[c] += g2 * f[c];
            }
            gs0 += g0; gs1 += g1; gs2 += g2;
        }
    }
    size_t base = (size_t)nid * 384 + lane * 8;
    uint4 o;
    o.x = (u32)f2b(a0[0]) | ((u32)f2b(a0[1]) << 16);
    o.y = (u32)f2b(a0[2]) | ((u32)f2b(a0[3]) << 16);
    o.z = (u32)f2b(a0[4]) | ((u32)f2b(a0[5]) << 16);
    o.w = (u32)f2b(a0[6]) | ((u32)f2b(a0[7]) << 16);
    *(uint4*)(t + base) = o;
    o.x = (u32)f2b(a1[0]) | ((u32)f2b(a1[1]) << 16);
    o.y = (u32)f2b(a1[2]) | ((u32)f2b(a1[3]) << 16);
    o.z = (u32)f2b(a1[4]) | ((u32)f2b(a1[5]) << 16);
    o.w = (u32)f2b(a1[6]) | ((u32)f2b(a1[7]) << 16);
    *(uint4*)(t + base + 128) = o;
    o.x = (u32)f2b(a2[0]) | ((u32)f2b(a2[1]) << 16);
    o.y = (u32)f2b(a2[2]) | ((u32)f2b(a2[3]) << 16);
    o.z = (u32)f2b(a2[4]) | ((u32)f2b(a2[5]) << 16);
    o.w = (u32)f2b(a2[6]) | ((u32)f2b(a2[7]) << 16);
    *(uint4*)(t + base + 256) = o;
    if (lane == 0) {
        sk[nid * 4 + 0] = gs0;
        sk[nid * 4 + 1] = gs1;
        sk[nid * 4 + 2] = gs2;
        sk[nid * 4 + 3] = 0.f;
    }
}

// ---- bf16 MFMA GEMM, 512 threads / 8 waves; out[M,128] = A @ Bt^T.
__global__ __launch_bounds__(512) void gemm_mfma(const void* __restrict__ Araw,
                                                 const u16* __restrict__ Bt,
                                                 int M, int KD,
                                                 const float* __restrict__ bias,
                                                 const float* __restrict__ sk,
                                                 u16* __restrict__ outB,
                                                 int mode,
                                                 float* __restrict__ bnred) {
    __shared__ u16 As[128 * 64];
    __shared__ u16 Bs[128 * 64];
    const int m0 = blockIdx.x * 128;
    const int tid = threadIdx.x;
    const int lane = tid & 63;
    const int w = tid >> 6;              // 0..7
    const int wr = w >> 1, wc = w & 1;   // wr 0..3, wc 0..1

    f32x4 acc[2][4];
#pragma unroll
    for (int m = 0; m < 2; m++)
#pragma unroll
        for (int n = 0; n < 4; n++) acc[m][n] = (f32x4){0.f, 0.f, 0.f, 0.f};

    for (int k0 = 0; k0 < KD; k0 += 64) {
        __syncthreads();
        if (mode == 0) {
            const float* Af = (const float*)Araw;
#pragma unroll
            for (int i = 0; i < 2; i++) {
                int idx = tid + i * 512;          // 0..1023
                int r = idx >> 3, g = idx & 7;
                int gs = g ^ (r & 7);
                uint4 av = make_uint4(0, 0, 0, 0);
                if (m0 + r < M) {
                    float4 v0 = *(const float4*)(Af + (size_t)(m0 + r) * KD + k0 + g * 8);
                    float4 v1 = *(const float4*)(Af + (size_t)(m0 + r) * KD + k0 + g * 8 + 4);
                    av.x = (u32)f2b(v0.x) | ((u32)f2b(v0.y) << 16);
                    av.y = (u32)f2b(v0.z) | ((u32)f2b(v0.w) << 16);
                    av.z = (u32)f2b(v1.x) | ((u32)f2b(v1.y) << 16);
                    av.w = (u32)f2b(v1.z) | ((u32)f2b(v1.w) << 16);
                }
                *(uint4*)(As + r * 64 + gs * 8) = av;
                uint4 bv = *(const uint4*)(Bt + (size_t)r * KD + k0 + g * 8);
                *(uint4*)(Bs + r * 64 + gs * 8) = bv;
            }
        } else {
            const u16* Ab = (const u16*)Araw;
#pragma unroll
            for (int i = 0; i < 2; i++) {
                int blk = w * 2 + i;                 // 0..15 -> 8 rows each
                int r = blk * 8 + (lane >> 3);
                int gsrc = (lane & 7) ^ (r & 7);
                const u16* gA = Ab + (size_t)(m0 + r) * KD + k0 + gsrc * 8;
                const u16* gB = Bt + (size_t)r * KD + k0 + gsrc * 8;
                __builtin_amdgcn_global_load_lds(
                    (const __attribute__((address_space(1))) void*)gA,
                    (__attribute__((address_space(3))) void*)(As + blk * 512 + lane * 8),
                    16, 0, 0);
                __builtin_amdgcn_global_load_lds(
                    (const __attribute__((address_space(1))) void*)gB,
                    (__attribute__((address_space(3))) void*)(Bs + blk * 512 + lane * 8),
                    16, 0, 0);
            }
        }
        __syncthreads();
#pragma unroll
        for (int kk = 0; kk < 2; kk++) {
            bf16x8 af[2], bfr[4];
#pragma unroll
            for (int m = 0; m < 2; m++) {
                int r = wr * 32 + m * 16 + (lane & 15);
                int g = (kk * 4 + (lane >> 4)) ^ (r & 7);
                af[m] = *(const bf16x8*)(As + r * 64 + g * 8);
            }
#pragma unroll
            for (int n = 0; n < 4; n++) {
                int r = wc * 64 + n * 16 + (lane & 15);
                int g = (kk * 4 + (lane >> 4)) ^ (r & 7);
                bfr[n] = *(const bf16x8*)(Bs + r * 64 + g * 8);
            }
#pragma unroll
            for (int m = 0; m < 2; m++)
#pragma unroll
                for (int n = 0; n < 4; n++)
                    acc[m][n] = __builtin_amdgcn_mfma_f32_16x16x32_bf16(af[m], bfr[n], acc[m][n], 0, 0, 0);
        }
    }

    if (mode == 0) {
#pragma unroll
        for (int n = 0; n < 4; n++) {
            int col = wc * 64 + n * 16 + (lane & 15);
            float bv = bias[col];
#pragma unroll
            for (int m = 0; m < 2; m++) {
#pragma unroll
                for (int j = 0; j < 4; j++) {
                    int row = m0 + wr * 32 + m * 16 + (lane >> 4) * 4 + j;
                    if (row < M) outB[(size_t)row * 128 + col] = f2b(acc[m][n][j] + bv);
                }
            }
        }
    } else {
        float colsum[4] = {0.f, 0.f, 0.f, 0.f};
        float colsq[4]  = {0.f, 0.f, 0.f, 0.f};
#pragma unroll
        for (int n = 0; n < 4; n++) {
            int col = wc * 64 + n * 16 + (lane & 15);
            float b0 = bias[col], b1 = bias[128 + col], b2 = bias[256 + col];
#pragma unroll
            for (int m = 0; m < 2; m++) {
#pragma unroll
                for (int j = 0; j < 4; j++) {
                    int row = m0 + wr * 32 + m * 16 + (lane >> 4) * 4 + j;
                    if (row < M) {
                        float4 skv = *(const float4*)(sk + row * 4);
                        float v = acc[m][n][j] + skv.x * b0 + skv.y * b1 + skv.z * b2;
                        outB[(size_t)row * 128 + col] = f2b(v);
                        colsum[n] += v;
                        colsq[n]  += v * v;
                    }
                }
            }
        }
        __syncthreads();
        float* red = (float*)As;         // 256 floats: [0:128] sum, [128:256] sq
        if (tid < 256) red[tid] = 0.f;
        __syncthreads();
#pragma unroll
        for (int n = 0; n < 4; n++) {
            float s = colsum[n], q = colsq[n];
            s += __shfl_xor(s, 16); s += __shfl_xor(s, 32);
            q += __shfl_xor(q, 16); q += __shfl_xor(q, 32);
            if (lane < 16) {
                int col = wc * 64 + n * 16 + lane;
                atomicAdd(&red[col], s);
                atomicAdd(&red[128 + col], q);
            }
        }
        __syncthreads();
        if (tid < 256) atomicAdd(&bnred[tid], red[tid]);
    }
}

// ---- hb = bf16( hb + relu((aggB-mean)*rstd*gamma + beta) )   (layers 0..L-2)
__global__ void bn_apply(u16* __restrict__ hb,
                         const u16* __restrict__ aggB,
                         const float* __restrict__ bnred,
                         const float* __restrict__ gamma, const float* __restrict__ beta,
                         float invN, int N) {
    int idx = blockIdx.x * 256 + threadIdx.x;   // 4-channel group index
    if (idx >= N * 32) return;
    int c4 = idx & 31;
    float4 s  = *(const float4*)(bnred + c4 * 4);
    float4 q  = *(const float4*)(bnred + 128 + c4 * 4);
    float4 ga = *(const float4*)(gamma + c4 * 4);
    float4 be = *(const float4*)(beta + c4 * 4);
    float4 sc, sh;
    {
        float m, v2;
        m = s.x * invN; v2 = q.x * invN - m * m; sc.x = ga.x * rsqrtf(v2 + 1e-5f); sh.x = be.x - m * sc.x;
        m = s.y * invN; v2 = q.y * invN - m * m; sc.y = ga.y * rsqrtf(v2 + 1e-5f); sh.y = be.y - m * sc.y;
        m = s.z * invN; v2 = q.z * invN - m * m; sc.z = ga.z * rsqrtf(v2 + 1e-5f); sh.z = be.z - m * sc.z;
        m = s.w * invN; v2 = q.w * invN - m * m; sc.w = ga.w * rsqrtf(v2 + 1e-5f); sh.w = be.w - m * sc.w;
    }
    uint2 av = ((const uint2*)aggB)[idx];
    uint2 hv = ((const uint2*)hb)[idx];
    float r0 = blo(hv.x) + fmaxf(blo(av.x) * sc.x + sh.x, 0.f);
    float r1 = bhi(hv.x) + fmaxf(bhi(av.x) * sc.y + sh.y, 0.f);
    float r2 = blo(hv.y) + fmaxf(blo(av.y) * sc.z + sh.z, 0.f);
    float r3 = bhi(hv.y) + fmaxf(bhi(av.y) * sc.w + sh.w, 0.f);
    uint2 o;
    o.x = (u32)f2b(r0) | ((u32)f2b(r1) << 16);
    o.y = (u32)f2b(r2) | ((u32)f2b(r3) << 16);
    ((uint2*)hb)[idx] = o;
}

// ---- readout with fused last-layer BN
__global__ void readout_bn_kernel(const u16* __restrict__ hb,
                                  const u16* __restrict__ aggB,
                                  const float* __restrict__ bnred,
                                  const float* __restrict__ gamma,
                                  const float* __restrict__ beta,
                                  float invN,
                                  const int* __restrict__ gids,
                                  float* __restrict__ hg, float* __restrict__ cnts, int N) {
    int c = threadIdx.x;    // 128 channels
    float s = bnred[c], q = bnred[128 + c];
    float mean = s * invN;
    float var  = q * invN - mean * mean;
    float sc = gamma[c] * rsqrtf(var + 1e-5f);
    float sh = beta[c] - mean * sc;
    int r0 = blockIdx.x * 25;
    if (r0 >= N) return;
    int r1 = min(r0 + 25, N);
    int cur = gids[r0];
    float acc = 0.f, cnt = 0.f;
    for (int r = r0; r < r1; r++) {
        int g = gids[r];
        if (g != cur) {
            atomicAdd(&hg[(size_t)cur * 128 + c], acc);
            if (c == 0) atomicAdd(&cnts[cur], cnt);
            acc = 0.f; cnt = 0.f; cur = g;
        }
        float hval = blo((u32)hb[(size_t)r * 128 + c]);
        float aval = blo((u32)aggB[(size_t)r * 128 + c]);
        acc += hval + fmaxf(aval * sc + sh, 0.f);
        cnt += 1.f;
    }
    atomicAdd(&hg[(size_t)cur * 128 + c], acc);
    if (c == 0) atomicAdd(&cnts[cur], cnt);
}

// ---- MLP readout
__global__ void mlp_kernel(const float* __restrict__ hg, const float* __restrict__ cnts,
                           const float* __restrict__ W1, const float* __restrict__ b1,
                           const float* __restrict__ W2, const float* __restrict__ b2,
                           const float* __restrict__ W3, const float* __restrict__ b3,
                           float* __restrict__ out) {
    __shared__ float v[128], y1[64], y2[32];
    int g = blockIdx.x, t = threadIdx.x;
    float inv = 1.0f / cnts[g];
    v[t] = hg[(size_t)g * 128 + t] * inv;
    __syncthreads();
    if (t < 64) {
        float a = b1[t];
        for (int k = 0; k < 128; k++) a += v[k] * W1[k * 64 + t];
        y1[t] = fmaxf(a, 0.f);
    }
    __syncthreads();
    if (t < 32) {
        float a = b2[t];
        for (int k = 0; k < 64; k++) a += y1[k] * W2[k * 32 + t];
        y2[t] = fmaxf(a, 0.f);
    }
    __syncthreads();
    if (t < 10) {
        float a = b3[t];
        for (int k = 0; k < 32; k++) a += y2[k] * W3[k * 10 + t];
        out[g * 10 + t] = a;
    }
}

extern "C" void kernel_launch(void* const* d_in, const int* in_sizes, int n_in,
                              void* d_out, int out_size, void* d_ws, size_t ws_size,
                              hipStream_t stream) {
    const float* x      = (const float*)d_in[0];
    const float* emb_W  = (const float*)d_in[1];
    const float* emb_b  = (const float*)d_in[2];
    const float* fc_W   = (const float*)d_in[3];
    const float* fc_b   = (const float*)d_in[4];
    const float* mu     = (const float*)d_in[5];
    const float* isig   = (const float*)d_in[6];
    const float* gamma  = (const float*)d_in[7];
    const float* beta   = (const float*)d_in[8];
    const float* ppW    = (const float*)d_in[9];
    const float* ppb    = (const float*)d_in[10];
    const float* W1     = (const float*)d_in[11];
    const float* b1     = (const float*)d_in[12];
    const float* W2     = (const float*)d_in[13];
    const float* b2     = (const float*)d_in[14];
    const float* W3     = (const float*)d_in[15];
    const float* b3     = (const float*)d_in[16];
    const int*   src    = (const int*)d_in[17];
    const int*   dst    = (const int*)d_in[18];
    const int*   gids   = (const int*)d_in[19];

    const int N = in_sizes[0] / 128;
    const int E = in_sizes[17];
    const int L = in_sizes[8] / 128;
    const int G = out_size / 10;
    const int npg = N / G;                 // 1000
    const int Epad = E + 16;
    float* out = (float*)d_out;

    char* wp = (char*)d_ws;
    auto alloc = [&](size_t bytes) {
        char* p = wp;
        wp += (bytes + 255) & ~(size_t)255;
        return (void*)p;
    };
    u16*   hb     = (u16*)alloc((size_t)N * 128 * 2);
    u16*   t      = (u16*)alloc((size_t)N * 384 * 2);
    u16*   aggB   = (u16*)alloc((size_t)N * 128 * 2);
    uint2* rec    = (uint2*)alloc((size_t)L * Epad * 8);
    int*   psrc   = (int*)alloc((size_t)E * 4);
    int*   pdst   = (int*)alloc((size_t)E * 4);
    u32*   tmp    = (u32*)alloc((size_t)E * 4);
    float* sk     = (float*)alloc((size_t)N * 4 * 4);
    int*   rs     = (int*)alloc((size_t)(N + 1) * 4);
    int*   gbase0 = (int*)alloc(256 * 4);
    u16*   wembt  = (u16*)alloc((size_t)128 * 128 * 2);
    u16*   wfct   = (u16*)alloc((size_t)L * 128 * 384 * 2);
    // contiguous zero-region: gtot, gcur, hg, cnts, bnAll -> ONE memset
    char*  z0     = wp;
    int*   gtot   = (int*)alloc(256 * 4);
    int*   gcur   = (int*)alloc(256 * 4);
    float* hg     = (float*)alloc((size_t)G * 128 * 4);
    float* cnts   = (float*)alloc((size_t)G * 4);
    float* bnAll  = (float*)alloc((size_t)L * 256 * 4);
    size_t zbytes = (size_t)(wp - z0);

    hipMemsetAsync(z0, 0, zbytes, stream);

    // weight prep (merged)
    const int totalFc = L * 128 * 384;
    prep_weights<<<(16384 + totalFc + 255) / 256, 256, 0, stream>>>(emb_W, wembt, fc_W, wfct, totalFc);

    // CSR build: graph hist -> graph scan -> bucketA -> bucketB (builds rs)
    ghist_kernel<<<(E + 4095) / 4096, 256, 0, stream>>>(dst, gtot, E, npg);
    gscan_kernel<<<1, 64, 0, stream>>>(gtot, gbase0, G);
    bucketA<<<(E + 4095) / 4096, 256, 0, stream>>>(src, dst, gbase0, gcur, tmp, E, npg, G);
    bucketB<<<G, 1024, 0, stream>>>(tmp, gbase0, rs, psrc, pdst, npg, G, N);
    gw_kernel<<<(Epad + 255) / 256, 256, 0, stream>>>(psrc, pdst, rs, ppW, ppb, mu, isig,
                                                      rec, E, Epad, L);

    // node embedding (fp32 x converted in staging)
    const int gblocks = (N + 127) / 128;
    gemm_mfma<<<gblocks, 512, 0, stream>>>(x, wembt, N, 128, emb_b, nullptr, hb, 0, nullptr);

    const float invN = 1.0f / (float)N;
    for (int l = 0; l < L; l++) {
        agg_kernel<<<(N + 15) / 16, 256, 0, stream>>>(hb, rec + (size_t)l * Epad, rs, t, sk, N);
        gemm_mfma<<<gblocks, 512, 0, stream>>>(t, wfct + (size_t)l * 128 * 384, N, 384,
                                               fc_b + (size_t)l * 384, sk, aggB, 1,
                                               bnAll + (size_t)l * 256);
        if (l < L - 1)
            bn_apply<<<(N * 32 + 255) / 256, 256, 0, stream>>>(hb, aggB, bnAll + (size_t)l * 256,
                                                               gamma + l * 128, beta + l * 128,
                                                               invN, N);
    }

    readout_bn_kernel<<<(N + 24) / 25, 128, 0, stream>>>(hb, aggB, bnAll + (size_t)(L - 1) * 256,
                                                         gamma + (L - 1) * 128, beta + (L - 1) * 128,
                                                         invN, gids, hg, cnts, N);
    mlp_kernel<<<G, 128, 0, stream>>>(hg, cnts, W1, b1, W2, b2, W3, b3, out);
}

// Round 19
// 366.082 us; speedup vs baseline: 1.0236x; 1.0236x over previous
//
#include <hip/hip_runtime.h>

// ---------------------------------------------------------------------------
// MoNet GNN: N=50000, E=800000, H=128, K=3, L=4, pdim=2, G=50, npg=1000
// Round 19: R17 structure restored (agg = quarter-wave 4-edge blocks, the
//           measured best; R18's 8-edge widening regressed). bn_apply widened
//           to 8 channels/thread (uint4). 8-wave 512-thread GEMM, graph-level
//           CSR, 8B bf16 edge records, bf16 h, BN fused in epilogue+readout.
// ---------------------------------------------------------------------------

typedef unsigned char  u8;
typedef unsigned short u16;
typedef unsigned int   u32;
typedef __attribute__((ext_vector_type(8))) short bf16x8;
typedef __attribute__((ext_vector_type(4))) float f32x4;

__device__ __forceinline__ u16 f2b(float f) {
    union { float f; u32 u; } v; v.f = f;
    u32 u = v.u;
    u32 r = (u + 0x7fffu + ((u >> 16) & 1u)) >> 16;   // RNE
    return (u16)r;
}
__device__ __forceinline__ float blo(u32 h) {
    union { u32 u; float f; } v; v.u = h << 16; return v.f;
}
__device__ __forceinline__ float bhi(u32 h) {
    union { u32 u; float f; } v; v.u = h & 0xffff0000u; return v.f;
}

// ---- merged weight prep: embW^T (16384 elems) then fcW B^T (L*128*384)
__global__ void prep_weights(const float* __restrict__ embW, u16* __restrict__ embT,
                             const float* __restrict__ fcW, u16* __restrict__ fcT,
                             int totalFc) {
    int idx = blockIdx.x * 256 + threadIdx.x;
    if (idx < 16384) {
        int n = idx >> 7, k = idx & 127;
        embT[idx] = f2b(embW[k * 128 + n]);
        return;
    }
    idx -= 16384;
    if (idx >= totalFc) return;
    int kk = idx % 384;
    int rest = idx / 384;
    int n = rest & 127;
    int l = rest >> 7;
    int kc = kk >> 7, r = kk & 127;
    fcT[idx] = f2b(fcW[((size_t)(l * 128 + r)) * 384 + kc * 128 + n]);
}

// ---- per-graph edge histogram (LDS-binned)
__global__ __launch_bounds__(256) void ghist_kernel(const int* __restrict__ dst,
                                                    int* __restrict__ gtot,
                                                    int E, int npg) {
    __shared__ int h[64];
    const int tid = threadIdx.x;
    if (tid < 64) h[tid] = 0;
    __syncthreads();
    int e0 = blockIdx.x * 4096;
    int n = min(4096, E - e0);
    for (int i = tid; i < n; i += 256) atomicAdd(&h[dst[e0 + i] / npg], 1);
    __syncthreads();
    if (tid < 64) { int v = h[tid]; if (v) atomicAdd(&gtot[tid], v); }
}

// ---- exclusive scan of gtot[G] -> gbase0[G+1]
__global__ void gscan_kernel(const int* __restrict__ gtot, int* __restrict__ gbase0, int G) {
    if (threadIdx.x == 0 && blockIdx.x == 0) {
        int acc = 0;
        for (int g = 0; g < G; g++) { gbase0[g] = acc; acc += gtot[g]; }
        gbase0[G] = acc;
    }
}

// ---- Pass A: bin 4096 edges per block by graph (LDS), chunk-copy to tmp
__global__ __launch_bounds__(256) void bucketA(const int* __restrict__ src,
                                               const int* __restrict__ dst,
                                               const int* __restrict__ gbase0,
                                               int* __restrict__ gcur,
                                               u32* __restrict__ tmp,
                                               int E, int npg, int G) {
    __shared__ u32 ebuf[4096];
    __shared__ u8  gmap[4096];
    __shared__ int ghist[64], gexc[64], gbase[64], lcur[64];
    const int tid = threadIdx.x;
    const int e0 = blockIdx.x * 4096;
    const int n = min(4096, E - e0);
    if (tid < 64) { ghist[tid] = 0; lcur[tid] = 0; }
    __syncthreads();
    for (int i = tid; i < n; i += 256) {
        int g = dst[e0 + i] / npg;
        atomicAdd(&ghist[g], 1);
    }
    __syncthreads();
    if (tid == 0) {
        int acc = 0;
        for (int g = 0; g < G; g++) { gexc[g] = acc; acc += ghist[g]; }
    }
    __syncthreads();
    if (tid < G) {
        int c = ghist[tid];
        gbase[tid] = (c > 0) ? gbase0[tid] + atomicAdd(&gcur[tid], c) : 0;
    }
    __syncthreads();
    for (int i = tid; i < n; i += 256) {
        int d = dst[e0 + i];
        int g = d / npg;
        int pos = gexc[g] + atomicAdd(&lcur[g], 1);
        ebuf[pos] = ((u32)src[e0 + i] << 16) | (u32)(d - g * npg);
        gmap[pos] = (u8)g;
    }
    __syncthreads();
    for (int i = tid; i < n; i += 256) {
        int g = gmap[i];
        tmp[gbase[g] + (i - gexc[g])] = ebuf[i];
    }
}

// ---- Pass B: one block per graph. Builds node-level rs (LDS hist + scan),
//      then counting-scatters psrc and fills pdst.
__global__ __launch_bounds__(1024) void bucketB(const u32* __restrict__ tmp,
                                                const int* __restrict__ gbase0,
                                                int* __restrict__ rs,
                                                int* __restrict__ psrc,
                                                int* __restrict__ pdst,
                                                int npg, int G, int N) {
    __shared__ int rsl[1025];
    __shared__ int lcur[1024];
    __shared__ int buf[1024];
    const int g = blockIdx.x, tid = threadIdx.x;
    const int base = g * npg;
    const int r0 = gbase0[g], r1 = gbase0[g + 1];
    if (tid < 1024) lcur[tid] = 0;
    __syncthreads();
    for (int p = r0 + tid; p < r1; p += 1024)
        atomicAdd(&lcur[tmp[p] & 0xffffu], 1);
    __syncthreads();
    int v = (tid < npg) ? lcur[tid] : 0;
    buf[tid] = v;
    __syncthreads();
    for (int off = 1; off < 1024; off <<= 1) {
        int x = (tid >= off) ? buf[tid - off] : 0;
        __syncthreads();
        buf[tid] += x;
        __syncthreads();
    }
    if (tid < npg) rsl[tid] = r0 + buf[tid] - v;
    if (tid == 0) rsl[npg] = r1;
    if (tid < 1024) lcur[tid] = 0;
    __syncthreads();
    for (int i = tid; i < npg; i += 1024) rs[base + i] = rsl[i];
    if (g == G - 1 && tid == 0) rs[N] = r1;
    for (int p = r0 + tid; p < r1; p += 1024) {
        u32 w = tmp[p];
        int dl = w & 0xffffu;
        int pos = rsl[dl] + atomicAdd(&lcur[dl], 1);
        psrc[pos] = (int)(w >> 16);
    }
    for (int i = tid; i < npg; i += 1024) {
        int a = rsl[i], b = rsl[i + 1];
        for (int p = a; p < b; p++) pdst[p] = base + i;
    }
}

// ---- build 8B edge records {u16 src | bf16 g0 <<16, bf16 g1 | bf16 g2 <<16}
__global__ void gw_kernel(const int* __restrict__ psrc, const int* __restrict__ pdst,
                          const int* __restrict__ rs,
                          const float* __restrict__ ppW, const float* __restrict__ ppb,
                          const float* __restrict__ mu, const float* __restrict__ isig,
                          uint2* __restrict__ rec, int E, int Epad, int L) {
    int p = blockIdx.x * 256 + threadIdx.x;
    if (p >= Epad) return;
    if (p >= E) {
        for (int l = 0; l < L; l++) rec[(size_t)l * Epad + p] = make_uint2(0u, 0u);
        return;
    }
    int s = psrc[p];
    int d = pdst[p];
    float ps0 = rsqrtf((float)(rs[s + 1] - rs[s]) + 1.0f);
    float ps1 = rsqrtf((float)(rs[d + 1] - rs[d]) + 1.0f);
    for (int l = 0; l < L; l++) {
        float p0 = tanhf(ps0 * ppW[l * 4 + 0] + ps1 * ppW[l * 4 + 2] + ppb[l * 2 + 0]);
        float p1 = tanhf(ps0 * ppW[l * 4 + 1] + ps1 * ppW[l * 4 + 3] + ppb[l * 2 + 1]);
        float g[3];
#pragma unroll
        for (int k = 0; k < 3; k++) {
            float d0 = (p0 - mu[(l * 3 + k) * 2 + 0]) * isig[(l * 3 + k) * 2 + 0];
            float d1 = (p1 - mu[(l * 3 + k) * 2 + 1]) * isig[(l * 3 + k) * 2 + 1];
            g[k] = expf(-0.5f * (d0 * d0 + d1 * d1));
        }
        uint2 r;
        r.x = (u32)s | ((u32)f2b(g[0]) << 16);
        r.y = (u32)f2b(g[1]) | ((u32)f2b(g[2]) << 16);
        rec[(size_t)l * Epad + p] = r;
    }
}

// ---- per-node aggregation: QUARTER-WAVE per node (16 lanes, 8 ch/lane).
//      Main: unmasked 4-edge blocks; tail: one masked 4-edge block. (R17)
__global__ __launch_bounds__(256) void agg_kernel(const u16* __restrict__ hb,
                                                  const uint2* __restrict__ rec,  // layer base
                                                  const int* __restrict__ rs,
                                                  u16* __restrict__ t,
                                                  float* __restrict__ sk, int N) {
    int nid = blockIdx.x * 16 + (threadIdx.x >> 4);
    if (nid >= N) return;
    int lane = threadIdx.x & 15;         // channels lane*8 .. lane*8+7
    int p0 = rs[nid], p1 = rs[nid + 1];
    float a0[8] = {}, a1[8] = {}, a2[8] = {};
    float gs0 = 0.f, gs1 = 0.f, gs2 = 0.f;
    int p = p0;
    for (; p + 4 <= p1; p += 4) {
        uint2 rv[4];
        uint4 hv[4];
#pragma unroll
        for (int j = 0; j < 4; j++) rv[j] = rec[p + j];
#pragma unroll
        for (int j = 0; j < 4; j++) {
            int s = rv[j].x & 0xffff;
            hv[j] = *(const uint4*)(hb + (size_t)s * 128 + lane * 8);
        }
#pragma unroll
        for (int j = 0; j < 4; j++) {
            float g0 = bhi(rv[j].x), g1 = blo(rv[j].y), g2 = bhi(rv[j].y);
            float f[8];
            f[0] = blo(hv[j].x); f[1] = bhi(hv[j].x);
            f[2] = blo(hv[j].y); f[3] = bhi(hv[j].y);
            f[4] = blo(hv[j].z); f[5] = bhi(hv[j].z);
            f[6] = blo(hv[j].w); f[7] = bhi(hv[j].w);
#pragma unroll
            for (int c = 0; c < 8; c++) {
                a0[c] += g0 * f[c];
                a1[c] += g1 * f[c];
                a2[c] += g2 * f[c];
            }
            gs0 += g0; gs1 += g1; gs2 += g2;
        }
    }
    if (p < p1) {
        uint2 rv[4];
        uint4 hv[4];
#pragma unroll
        for (int j = 0; j < 4; j++) rv[j] = rec[p + j];
#pragma unroll
        for (int j = 0; j < 4; j++) {
            int s = rv[j].x & 0xffff;
            hv[j] = *(const uint4*)(hb + (size_t)s * 128 + lane * 8);
        }
#pragma unroll
        for (int j = 0; j < 4; j++) {
            bool ok = (p + j) < p1;
            float g0 = ok ? bhi(rv[j].x) : 0.f;
            float g1 = ok ? blo(rv[j].y) : 0.f;
            float g2 = ok ? bhi(rv[j].y) : 0.f;
            float f[8];
            f[0] = blo(hv[j].x); f[1] = bhi(hv[j].x);
            f[2] = blo(hv[j].y); f[3] = bhi(hv[j].y);
            f[4] = blo(hv[j].z); f[5] = bhi(hv[j].z);
            f[6] = blo(hv[j].w); f[7] = bhi(hv[j].w);
#pragma unroll
            for (int c = 0; c < 8; c++) {
                a0[c] += g0 * f[c];
                a1[c] += g1 * f[c];
                a2[c] += g2 * f[c];
            }
            gs0 += g0; gs1 += g1; gs2 += g2;
        }
    }
    size_t base = (size_t)nid * 384 + lane * 8;
    uint4 o;
    o.x = (u32)f2b(a0[0]) | ((u32)f2b(a0[1]) << 16);
    o.y = (u32)f2b(a0[2]) | ((u32)f2b(a0[3]) << 16);
    o.z = (u32)f2b(a0[4]) | ((u32)f2b(a0[5]) << 16);
    o.w = (u32)f2b(a0[6]) | ((u32)f2b(a0[7]) << 16);
    *(uint4*)(t + base) = o;
    o.x = (u32)f2b(a1[0]) | ((u32)f2b(a1[1]) << 16);
    o.y = (u32)f2b(a1[2]) | ((u32)f2b(a1[3]) << 16);
    o.z = (u32)f2b(a1[4]) | ((u32)f2b(a1[5]) << 16);
    o.w = (u32)f2b(a1[6]) | ((u32)f2b(a1[7]) << 16);
    *(uint4*)(t + base + 128) = o;
    o.x = (u32)f2b(a2[0]) | ((u32)f2b(a2[1]) << 16);
    o.y = (u32)f2b(a2[2]) | ((u32)f2b(a2[3]) << 16);
    o.z = (u32)f2b(a2[4]) | ((u32)f2b(a2[5]) << 16);
    o.w = (u32)f2b(a2[6]) | ((u32)f2b(a2[7]) << 16);
    *(uint4*)(t + base + 256) = o;
    if (lane == 0) {
        sk[nid * 4 + 0] = gs0;
        sk[nid * 4 + 1] = gs1;
        sk[nid * 4 + 2] = gs2;
        sk[nid * 4 + 3] = 0.f;
    }
}

// ---- bf16 MFMA GEMM, 512 threads / 8 waves; out[M,128] = A @ Bt^T.
__global__ __launch_bounds__(512) void gemm_mfma(const void* __restrict__ Araw,
                                                 const u16* __restrict__ Bt,
                                                 int M, int KD,
                                                 const float* __restrict__ bias,
                                                 const float* __restrict__ sk,
                                                 u16* __restrict__ outB,
                                                 int mode,
                                                 float* __restrict__ bnred) {
    __shared__ u16 As[128 * 64];
    __shared__ u16 Bs[128 * 64];
    const int m0 = blockIdx.x * 128;
    const int tid = threadIdx.x;
    const int lane = tid & 63;
    const int w = tid >> 6;              // 0..7
    const int wr = w >> 1, wc = w & 1;   // wr 0..3, wc 0..1

    f32x4 acc[2][4];
#pragma unroll
    for (int m = 0; m < 2; m++)
#pragma unroll
        for (int n = 0; n < 4; n++) acc[m][n] = (f32x4){0.f, 0.f, 0.f, 0.f};

    for (int k0 = 0; k0 < KD; k0 += 64) {
        __syncthreads();
        if (mode == 0) {
            const float* Af = (const float*)Araw;
#pragma unroll
            for (int i = 0; i < 2; i++) {
                int idx = tid + i * 512;          // 0..1023
                int r = idx >> 3, g = idx & 7;
                int gs = g ^ (r & 7);
                uint4 av = make_uint4(0, 0, 0, 0);
                if (m0 + r < M) {
                    float4 v0 = *(const float4*)(Af + (size_t)(m0 + r) * KD + k0 + g * 8);
                    float4 v1 = *(const float4*)(Af + (size_t)(m0 + r) * KD + k0 + g * 8 + 4);
                    av.x = (u32)f2b(v0.x) | ((u32)f2b(v0.y) << 16);
                    av.y = (u32)f2b(v0.z) | ((u32)f2b(v0.w) << 16);
                    av.z = (u32)f2b(v1.x) | ((u32)f2b(v1.y) << 16);
                    av.w = (u32)f2b(v1.z) | ((u32)f2b(v1.w) << 16);
                }
                *(uint4*)(As + r * 64 + gs * 8) = av;
                uint4 bv = *(const uint4*)(Bt + (size_t)r * KD + k0 + g * 8);
                *(uint4*)(Bs + r * 64 + gs * 8) = bv;
            }
        } else {
            const u16* Ab = (const u16*)Araw;
#pragma unroll
            for (int i = 0; i < 2; i++) {
                int blk = w * 2 + i;                 // 0..15 -> 8 rows each
                int r = blk * 8 + (lane >> 3);
                int gsrc = (lane & 7) ^ (r & 7);
                const u16* gA = Ab + (size_t)(m0 + r) * KD + k0 + gsrc * 8;
                const u16* gB = Bt + (size_t)r * KD + k0 + gsrc * 8;
                __builtin_amdgcn_global_load_lds(
                    (const __attribute__((address_space(1))) void*)gA,
                    (__attribute__((address_space(3))) void*)(As + blk * 512 + lane * 8),
                    16, 0, 0);
                __builtin_amdgcn_global_load_lds(
                    (const __attribute__((address_space(1))) void*)gB,
                    (__attribute__((address_space(3))) void*)(Bs + blk * 512 + lane * 8),
                    16, 0, 0);
            }
        }
        __syncthreads();
#pragma unroll
        for (int kk = 0; kk < 2; kk++) {
            bf16x8 af[2], bfr[4];
#pragma unroll
            for (int m = 0; m < 2; m++) {
                int r = wr * 32 + m * 16 + (lane & 15);
                int g = (kk * 4 + (lane >> 4)) ^ (r & 7);
                af[m] = *(const bf16x8*)(As + r * 64 + g * 8);
            }
#pragma unroll
            for (int n = 0; n < 4; n++) {
                int r = wc * 64 + n * 16 + (lane & 15);
                int g = (kk * 4 + (lane >> 4)) ^ (r & 7);
                bfr[n] = *(const bf16x8*)(Bs + r * 64 + g * 8);
            }
#pragma unroll
            for (int m = 0; m < 2; m++)
#pragma unroll
                for (int n = 0; n < 4; n++)
                    acc[m][n] = __builtin_amdgcn_mfma_f32_16x16x32_bf16(af[m], bfr[n], acc[m][n], 0, 0, 0);
        }
    }

    if (mode == 0) {
#pragma unroll
        for (int n = 0; n < 4; n++) {
            int col = wc * 64 + n * 16 + (lane & 15);
            float bv = bias[col];
#pragma unroll
            for (int m = 0; m < 2; m++) {
#pragma unroll
                for (int j = 0; j < 4; j++) {
                    int row = m0 + wr * 32 + m * 16 + (lane >> 4) * 4 + j;
                    if (row < M) outB[(size_t)row * 128 + col] = f2b(acc[m][n][j] + bv);
                }
            }
        }
    } else {
        float colsum[4] = {0.f, 0.f, 0.f, 0.f};
        float colsq[4]  = {0.f, 0.f, 0.f, 0.f};
#pragma unroll
        for (int n = 0; n < 4; n++) {
            int col = wc * 64 + n * 16 + (lane & 15);
            float b0 = bias[col], b1 = bias[128 + col], b2 = bias[256 + col];
#pragma unroll
            for (int m = 0; m < 2; m++) {
#pragma unroll
                for (int j = 0; j < 4; j++) {
                    int row = m0 + wr * 32 + m * 16 + (lane >> 4) * 4 + j;
                    if (row < M) {
                        float4 skv = *(const float4*)(sk + row * 4);
                        float v = acc[m][n][j] + skv.x * b0 + skv.y * b1 + skv.z * b2;
                        outB[(size_t)row * 128 + col] = f2b(v);
                        colsum[n] += v;
                        colsq[n]  += v * v;
                    }
                }
            }
        }
        __syncthreads();
        float* red = (float*)As;         // 256 floats: [0:128] sum, [128:256] sq
        if (tid < 256) red[tid] = 0.f;
        __syncthreads();
#pragma unroll
        for (int n = 0; n < 4; n++) {
            float s = colsum[n], q = colsq[n];
            s += __shfl_xor(s, 16); s += __shfl_xor(s, 32);
            q += __shfl_xor(q, 16); q += __shfl_xor(q, 32);
            if (lane < 16) {
                int col = wc * 64 + n * 16 + lane;
                atomicAdd(&red[col], s);
                atomicAdd(&red[128 + col], q);
            }
        }
        __syncthreads();
        if (tid < 256) atomicAdd(&bnred[tid], red[tid]);
    }
}

// ---- hb = bf16( hb + relu((aggB-mean)*rstd*gamma + beta) ), 8 ch/thread
__global__ void bn_apply(u16* __restrict__ hb,
                         const u16* __restrict__ aggB,
                         const float* __restrict__ bnred,
                         const float* __restrict__ gamma, const float* __restrict__ beta,
                         float invN, int N) {
    int idx = blockIdx.x * 256 + threadIdx.x;   // 8-channel group index
    if (idx >= N * 16) return;
    int c8 = idx & 15;
    float sc[8], sh[8];
#pragma unroll
    for (int k = 0; k < 8; k++) {
        int c = c8 * 8 + k;
        float m = bnred[c] * invN;
        float v2 = bnred[128 + c] * invN - m * m;
        sc[k] = gamma[c] * rsqrtf(v2 + 1e-5f);
        sh[k] = beta[c] - m * sc[k];
    }
    uint4 av = ((const uint4*)aggB)[idx];
    uint4 hv = ((const uint4*)hb)[idx];
    float a[8] = { blo(av.x), bhi(av.x), blo(av.y), bhi(av.y),
                   blo(av.z), bhi(av.z), blo(av.w), bhi(av.w) };
    float h[8] = { blo(hv.x), bhi(hv.x), blo(hv.y), bhi(hv.y),
                   blo(hv.z), bhi(hv.z), blo(hv.w), bhi(hv.w) };
    u32 r[8];
#pragma unroll
    for (int k = 0; k < 8; k++)
        r[k] = (u32)f2b(h[k] + fmaxf(a[k] * sc[k] + sh[k], 0.f));
    uint4 o;
    o.x = r[0] | (r[1] << 16);
    o.y = r[2] | (r[3] << 16);
    o.z = r[4] | (r[5] << 16);
    o.w = r[6] | (r[7] << 16);
    ((uint4*)hb)[idx] = o;
}

// ---- readout with fused last-layer BN
__global__ void readout_bn_kernel(const u16* __restrict__ hb,
                                  const u16* __restrict__ aggB,
                                  const float* __restrict__ bnred,
                                  const float* __restrict__ gamma,
                                  const float* __restrict__ beta,
                                  float invN,
                                  const int* __restrict__ gids,
                                  float* __restrict__ hg, float* __restrict__ cnts, int N) {
    int c = threadIdx.x;    // 128 channels
    float s = bnred[c], q = bnred[128 + c];
    float mean = s * invN;
    float var  = q * invN - mean * mean;
    float sc = gamma[c] * rsqrtf(var + 1e-5f);
    float sh = beta[c] - mean * sc;
    int r0 = blockIdx.x * 25;
    if (r0 >= N) return;
    int r1 = min(r0 + 25, N);
    int cur = gids[r0];
    float acc = 0.f, cnt = 0.f;
    for (int r = r0; r < r1; r++) {
        int g = gids[r];
        if (g != cur) {
            atomicAdd(&hg[(size_t)cur * 128 + c], acc);
            if (c == 0) atomicAdd(&cnts[cur], cnt);
            acc = 0.f; cnt = 0.f; cur = g;
        }
        float hval = blo((u32)hb[(size_t)r * 128 + c]);
        float aval = blo((u32)aggB[(size_t)r * 128 + c]);
        acc += hval + fmaxf(aval * sc + sh, 0.f);
        cnt += 1.f;
    }
    atomicAdd(&hg[(size_t)cur * 128 + c], acc);
    if (c == 0) atomicAdd(&cnts[cur], cnt);
}

// ---- MLP readout
__global__ void mlp_kernel(const float* __restrict__ hg, const float* __restrict__ cnts,
                           const float* __restrict__ W1, const float* __restrict__ b1,
                           const float* __restrict__ W2, const float* __restrict__ b2,
                           const float* __restrict__ W3, const float* __restrict__ b3,
                           float* __restrict__ out) {
    __shared__ float v[128], y1[64], y2[32];
    int g = blockIdx.x, t = threadIdx.x;
    float inv = 1.0f / cnts[g];
    v[t] = hg[(size_t)g * 128 + t] * inv;
    __syncthreads();
    if (t < 64) {
        float a = b1[t];
        for (int k = 0; k < 128; k++) a += v[k] * W1[k * 64 + t];
        y1[t] = fmaxf(a, 0.f);
    }
    __syncthreads();
    if (t < 32) {
        float a = b2[t];
        for (int k = 0; k < 64; k++) a += y1[k] * W2[k * 32 + t];
        y2[t] = fmaxf(a, 0.f);
    }
    __syncthreads();
    if (t < 10) {
        float a = b3[t];
        for (int k = 0; k < 32; k++) a += y2[k] * W3[k * 10 + t];
        out[g * 10 + t] = a;
    }
}

extern "C" void kernel_launch(void* const* d_in, const int* in_sizes, int n_in,
                              void* d_out, int out_size, void* d_ws, size_t ws_size,
                              hipStream_t stream) {
    const float* x      = (const float*)d_in[0];
    const float* emb_W  = (const float*)d_in[1];
    const float* emb_b  = (const float*)d_in[2];
    const float* fc_W   = (const float*)d_in[3];
    const float* fc_b   = (const float*)d_in[4];
    const float* mu     = (const float*)d_in[5];
    const float* isig   = (const float*)d_in[6];
    const float* gamma  = (const float*)d_in[7];
    const float* beta   = (const float*)d_in[8];
    const float* ppW    = (const float*)d_in[9];
    const float* ppb    = (const float*)d_in[10];
    const float* W1     = (const float*)d_in[11];
    const float* b1     = (const float*)d_in[12];
    const float* W2     = (const float*)d_in[13];
    const float* b2     = (const float*)d_in[14];
    const float* W3     = (const float*)d_in[15];
    const float* b3     = (const float*)d_in[16];
    const int*   src    = (const int*)d_in[17];
    const int*   dst    = (const int*)d_in[18];
    const int*   gids   = (const int*)d_in[19];

    const int N = in_sizes[0] / 128;
    const int E = in_sizes[17];
    const int L = in_sizes[8] / 128;
    const int G = out_size / 10;
    const int npg = N / G;                 // 1000
    const int Epad = E + 16;
    float* out = (float*)d_out;

    char* wp = (char*)d_ws;
    auto alloc = [&](size_t bytes) {
        char* p = wp;
        wp += (bytes + 255) & ~(size_t)255;
        return (void*)p;
    };
    u16*   hb     = (u16*)alloc((size_t)N * 128 * 2);
    u16*   t      = (u16*)alloc((size_t)N * 384 * 2);
    u16*   aggB   = (u16*)alloc((size_t)N * 128 * 2);
    uint2* rec    = (uint2*)alloc((size_t)L * Epad * 8);
    int*   psrc   = (int*)alloc((size_t)E * 4);
    int*   pdst   = (int*)alloc((size_t)E * 4);
    u32*   tmp    = (u32*)alloc((size_t)E * 4);
    float* sk     = (float*)alloc((size_t)N * 4 * 4);
    int*   rs     = (int*)alloc((size_t)(N + 1) * 4);
    int*   gbase0 = (int*)alloc(256 * 4);
    u16*   wembt  = (u16*)alloc((size_t)128 * 128 * 2);
    u16*   wfct   = (u16*)alloc((size_t)L * 128 * 384 * 2);
    // contiguous zero-region: gtot, gcur, hg, cnts, bnAll -> ONE memset
    char*  z0     = wp;
    int*   gtot   = (int*)alloc(256 * 4);
    int*   gcur   = (int*)alloc(256 * 4);
    float* hg     = (float*)alloc((size_t)G * 128 * 4);
    float* cnts   = (float*)alloc((size_t)G * 4);
    float* bnAll  = (float*)alloc((size_t)L * 256 * 4);
    size_t zbytes = (size_t)(wp - z0);

    hipMemsetAsync(z0, 0, zbytes, stream);

    // weight prep (merged)
    const int totalFc = L * 128 * 384;
    prep_weights<<<(16384 + totalFc + 255) / 256, 256, 0, stream>>>(emb_W, wembt, fc_W, wfct, totalFc);

    // CSR build: graph hist -> graph scan -> bucketA -> bucketB (builds rs)
    ghist_kernel<<<(E + 4095) / 4096, 256, 0, stream>>>(dst, gtot, E, npg);
    gscan_kernel<<<1, 64, 0, stream>>>(gtot, gbase0, G);
    bucketA<<<(E + 4095) / 4096, 256, 0, stream>>>(src, dst, gbase0, gcur, tmp, E, npg, G);
    bucketB<<<G, 1024, 0, stream>>>(tmp, gbase0, rs, psrc, pdst, npg, G, N);
    gw_kernel<<<(Epad + 255) / 256, 256, 0, stream>>>(psrc, pdst, rs, ppW, ppb, mu, isig,
                                                      rec, E, Epad, L);

    // node embedding (fp32 x converted in staging)
    const int gblocks = (N + 127) / 128;
    gemm_mfma<<<gblocks, 512, 0, stream>>>(x, wembt, N, 128, emb_b, nullptr, hb, 0, nullptr);

    const float invN = 1.0f / (float)N;
    for (int l = 0; l < L; l++) {
        agg_kernel<<<(N + 15) / 16, 256, 0, stream>>>(hb, rec + (size_t)l * Epad, rs, t, sk, N);
        gemm_mfma<<<gblocks, 512, 0, stream>>>(t, wfct + (size_t)l * 128 * 384, N, 384,
                                               fc_b + (size_t)l * 384, sk, aggB, 1,
                                               bnAll + (size_t)l * 256);
        if (l < L - 1)
            bn_apply<<<(N * 16 + 255) / 256, 256, 0, stream>>>(hb, aggB, bnAll + (size_t)l * 256,
                                                               gamma + l * 128, beta + l * 128,
                                                               invN, N);
    }

    readout_bn_kernel<<<(N + 24) / 25, 128, 0, stream>>>(hb, aggB, bnAll + (size_t)(L - 1) * 256,
                                                         gamma + (L - 1) * 128, beta + (L - 1) * 128,
                                                         invN, gids, hg, cnts, N);
    mlp_kernel<<<G, 128, 0, stream>>>(hg, cnts, W1, b1, W2, b2, W3, b3, out);
}